// Round 1
// baseline (615.555 us; speedup 1.0000x reference)
//
#include <hip/hip_runtime.h>
#include <math.h>

#define K_DIM 2048
#define M_DIM 512
#define N_DIM 64
#define EPSF 1e-8f
#define ROWS 8
#define TPB 512

typedef float f32x4 __attribute__((ext_vector_type(4)));

// ---------------------------------------------------------------------------
// Kernel A: per-column n, thr = L-th largest of w_b[:,n]; write scores_hard.
// thr = min{ v in column : count(column > v) <= L-1 }  (duplicate-safe)
// ---------------------------------------------------------------------------
__global__ __launch_bounds__(256) void thr_hard_kernel(
    const float* __restrict__ w_b, const int* __restrict__ lptr,
    float* __restrict__ scores_hard) {
  __shared__ float col[M_DIM];
  __shared__ float red[256];
  const int n = blockIdx.x;   // 0..N-1
  const int t = threadIdx.x;  // 0..255
  const int L = lptr[0];

  col[t]       = w_b[t * N_DIM + n];
  col[t + 256] = w_b[(t + 256) * N_DIM + n];
  __syncthreads();

  const float v0 = col[t], v1 = col[t + 256];
  int c0 = 0, c1 = 0;
  for (int i = 0; i < M_DIM; ++i) {
    const float c = col[i];  // broadcast read, conflict-free
    c0 += (c > v0);
    c1 += (c > v1);
  }
  float cand0 = (c0 <= L - 1) ? v0 : INFINITY;
  float cand1 = (c1 <= L - 1) ? v1 : INFINITY;
  red[t] = fminf(cand0, cand1);
  __syncthreads();
  for (int s = 128; s > 0; s >>= 1) {
    if (t < s) red[t] = fminf(red[t], red[t + s]);
    __syncthreads();
  }
  const float thr = red[0];

  // scores_hard[m][n] = (clip(w_b - thr + EPS, -1, 1) + 1) * 0.5
  {
    float sh0 = (col[t] - thr) + EPSF;
    float sh1 = (col[t + 256] - thr) + EPSF;
    sh0 = fminf(fmaxf(sh0, -1.0f), 1.0f);
    sh1 = fminf(fmaxf(sh1, -1.0f), 1.0f);
    scores_hard[t * N_DIM + n]         = (sh0 + 1.0f) * 0.5f;
    scores_hard[(t + 256) * N_DIM + n] = (sh1 + 1.0f) * 0.5f;
  }
}

// ---------------------------------------------------------------------------
// Fused kernel: GEMM (S = x @ w_att) -> row softmax -> combine.
// 256 blocks x 512 threads (8 waves = 2 waves/SIMD). Block b owns k-rows
// [8b, 8b+8). Phases:
//   1) stage x tile (8x512, 16 KiB) into LDS via float4
//   2) GEMM: thread t computes S[k0+r][t] for r=0..7 (x broadcast from LDS,
//      w column loads coalesced 256 B/wave, L2-resident)
//   3) softmax: wave r owns row r; 8 vals/lane + 6-step shfl_xor reduce
//   4) write soft (float4, NT), then stream 2 MiB of out/mw per block with
//      coalesced non-temporal b128 stores (long-running blocks -> no
//      dispatch-rate limit, fill-kernel-like write regime)
// ---------------------------------------------------------------------------
__global__ __launch_bounds__(TPB) void fused_kernel(
    const float* __restrict__ x, const float* __restrict__ w,
    const float* __restrict__ hard, float* __restrict__ soft,
    f32x4* __restrict__ out, f32x4* __restrict__ mw) {
  __shared__ float xs[ROWS][M_DIM];  // 16 KiB x tile
  __shared__ float sm[ROWS][M_DIM];  // 16 KiB soft rows
  const int t = threadIdx.x;         // 0..511
  const int k0 = blockIdx.x * ROWS;

  // ---- phase 1: stage x tile ----
  {
    const f32x4* xg = (const f32x4*)(x + (size_t)k0 * M_DIM);
    f32x4* xsv = (f32x4*)&xs[0][0];
    xsv[t]       = xg[t];
    xsv[t + TPB] = xg[t + TPB];
  }
  __syncthreads();

  // ---- phase 2: GEMM, one output column per thread ----
  float acc[ROWS];
#pragma unroll
  for (int r = 0; r < ROWS; ++r) acc[r] = 0.0f;

#pragma unroll 2
  for (int m = 0; m < M_DIM; m += 4) {
    const float w0 = w[(m + 0) * M_DIM + t];
    const float w1 = w[(m + 1) * M_DIM + t];
    const float w2 = w[(m + 2) * M_DIM + t];
    const float w3 = w[(m + 3) * M_DIM + t];
#pragma unroll
    for (int r = 0; r < ROWS; ++r) {
      const float4 xv = *(const float4*)&xs[r][m];  // broadcast b128 read
      acc[r] += xv.x * w0 + xv.y * w1 + xv.z * w2 + xv.w * w3;
    }
  }
#pragma unroll
  for (int r = 0; r < ROWS; ++r) sm[r][t] = acc[r];
  __syncthreads();

  // ---- phase 3: softmax, one row per wave ----
  {
    const int r = t >> 6, ln = t & 63;
    float v[8];
    float mx = -INFINITY;
#pragma unroll
    for (int i = 0; i < 8; ++i) {
      v[i] = sm[r][ln + 64 * i];
      mx = fmaxf(mx, v[i]);
    }
#pragma unroll
    for (int s = 32; s > 0; s >>= 1) mx = fmaxf(mx, __shfl_xor(mx, s));
    float sum = 0.0f;
#pragma unroll
    for (int i = 0; i < 8; ++i) {
      v[i] = expf(v[i] - mx);
      sum += v[i];
    }
#pragma unroll
    for (int s = 32; s > 0; s >>= 1) sum += __shfl_xor(sum, s);
    const float inv = 1.0f / sum;
#pragma unroll
    for (int i = 0; i < 8; ++i) sm[r][ln + 64 * i] = v[i] * inv + EPSF;
  }
  __syncthreads();

  // ---- phase 4a: write scores_soft (vectorized NT stores) ----
  {
    const f32x4* smv = (const f32x4*)&sm[0][0];
    f32x4* sg = (f32x4*)(soft + (size_t)k0 * M_DIM);
    __builtin_nontemporal_store(smv[t], &sg[t]);
    __builtin_nontemporal_store(smv[t + TPB], &sg[t + TPB]);
  }

  // ---- phase 4b: combine, stream out/mw (2 MiB per block) ----
  // global float4 index = k0*512*16 + g, g = it*512 + t;
  // g decomposes as (r*512 + m)*16 + q  -> perfectly coalesced stores.
  const f32x4* hard4 = (const f32x4*)hard;
  const size_t base = (size_t)k0 * (M_DIM * (N_DIM / 4));
#pragma unroll 4
  for (int it = 0; it < (ROWS * M_DIM * 16) / TPB; ++it) {
    const int g = it * TPB + t;
    const int q = g & 15;           // float4 index within n-row
    const int pair = g >> 4;        // r*512 + m
    const int m = pair & (M_DIM - 1);
    const int r = pair >> 9;
    const float ss = sm[r][m];      // LDS broadcast (16 lanes/addr, free)
    const float xv = xs[r][m];
    const f32x4 sh = hard4[m * 16 + q];  // L2-resident, 1 KiB/wave coalesced
    const f32x4 wgt = sh * ss;
    const f32x4 o = wgt * xv;
    __builtin_nontemporal_store(o, &out[base + g]);
    __builtin_nontemporal_store(wgt, &mw[base + g]);
  }
}

// ---------------------------------------------------------------------------
extern "C" void kernel_launch(void* const* d_in, const int* in_sizes, int n_in,
                              void* d_out, int out_size, void* d_ws,
                              size_t ws_size, hipStream_t stream) {
  const float* x     = (const float*)d_in[0];
  const float* w_att = (const float*)d_in[1];
  const float* w_b   = (const float*)d_in[2];
  const int*   lptr  = (const int*)d_in[3];

  float* out_base = (float*)d_out;
  const size_t OUT_SZ = (size_t)K_DIM * M_DIM * N_DIM;  // 67,108,864
  float* out0 = out_base;                               // out [K,M,N]
  float* hard = out0 + OUT_SZ;                          // scores_hard [M,N]
  float* soft = hard + (size_t)M_DIM * N_DIM;           // scores_soft [K,M]
  float* mwp  = soft + (size_t)K_DIM * M_DIM;           // mask_weight [K,M,N]

  thr_hard_kernel<<<N_DIM, 256, 0, stream>>>(w_b, lptr, hard);
  fused_kernel<<<K_DIM / ROWS, TPB, 0, stream>>>(
      x, w_att, hard, soft, (f32x4*)out0, (f32x4*)mwp);
}

// Round 2
// 578.344 us; speedup vs baseline: 1.0643x; 1.0643x over previous
//
#include <hip/hip_runtime.h>
#include <math.h>

#define K_DIM 2048
#define M_DIM 512
#define N_DIM 64
#define EPSF 1e-8f
#define ROWS 8
#define TPB 512

typedef float f32x4 __attribute__((ext_vector_type(4)));

// ---------------------------------------------------------------------------
// Kernel A: per-column n, thr = L-th largest of w_b[:,n]; write scores_hard.
// thr = min{ v in column : count(column > v) <= L-1 }  (duplicate-safe)
// ---------------------------------------------------------------------------
__global__ __launch_bounds__(256) void thr_hard_kernel(
    const float* __restrict__ w_b, const int* __restrict__ lptr,
    float* __restrict__ scores_hard) {
  __shared__ float col[M_DIM];
  __shared__ float red[256];
  const int n = blockIdx.x;   // 0..N-1
  const int t = threadIdx.x;  // 0..255
  const int L = lptr[0];

  col[t]       = w_b[t * N_DIM + n];
  col[t + 256] = w_b[(t + 256) * N_DIM + n];
  __syncthreads();

  const float v0 = col[t], v1 = col[t + 256];
  int c0 = 0, c1 = 0;
  for (int i = 0; i < M_DIM; ++i) {
    const float c = col[i];  // broadcast read, conflict-free
    c0 += (c > v0);
    c1 += (c > v1);
  }
  float cand0 = (c0 <= L - 1) ? v0 : INFINITY;
  float cand1 = (c1 <= L - 1) ? v1 : INFINITY;
  red[t] = fminf(cand0, cand1);
  __syncthreads();
  for (int s = 128; s > 0; s >>= 1) {
    if (t < s) red[t] = fminf(red[t], red[t + s]);
    __syncthreads();
  }
  const float thr = red[0];

  // scores_hard[m][n] = (clip(w_b - thr + EPS, -1, 1) + 1) * 0.5
  {
    float sh0 = (col[t] - thr) + EPSF;
    float sh1 = (col[t + 256] - thr) + EPSF;
    sh0 = fminf(fmaxf(sh0, -1.0f), 1.0f);
    sh1 = fminf(fmaxf(sh1, -1.0f), 1.0f);
    scores_hard[t * N_DIM + n]         = (sh0 + 1.0f) * 0.5f;
    scores_hard[(t + 256) * N_DIM + n] = (sh1 + 1.0f) * 0.5f;
  }
}

// ---------------------------------------------------------------------------
// Fused kernel v2: GEMM (S = x @ w_att) -> row softmax -> combine.
// 256 blocks x 512 threads (8 waves = 2/SIMD), block b owns k-rows [8b,8b+8).
// GEMM: two row-groups (t>>8), each thread does 4 rows x 2 cols ->
//   4 broadcast ds_read_b128 per wave per m-step (8 FMA per LDS read),
//   w loads coalesced + L1-reused across the block's waves.
// Combine: PLAIN b128 stores (NT removed — fill kernel proves plain streaming
//   writes hit 6.2 TB/s; NT suspected of capping us at ~2 TB/s).
// ---------------------------------------------------------------------------
__global__ __launch_bounds__(TPB) void fused_kernel(
    const float* __restrict__ x, const float* __restrict__ w,
    const float* __restrict__ hard, float* __restrict__ soft,
    f32x4* __restrict__ out, f32x4* __restrict__ mw) {
  __shared__ float xs[ROWS][M_DIM];  // 16 KiB x tile
  __shared__ float sm[ROWS][M_DIM];  // 16 KiB soft rows
  const int t = threadIdx.x;         // 0..511
  const int k0 = blockIdx.x * ROWS;

  // ---- phase 1: stage x tile ----
  {
    const f32x4* xg = (const f32x4*)(x + (size_t)k0 * M_DIM);
    f32x4* xsv = (f32x4*)&xs[0][0];
    xsv[t]       = xg[t];
    xsv[t + TPB] = xg[t + TPB];
  }
  __syncthreads();

  // ---- phase 2: GEMM, 4 rows x 2 cols per thread ----
  {
    const int half = t >> 8;      // wave-uniform row-group (0/1)
    const int j0 = t & 255;       // first owned column
    const int r0 = half * 4;
    float acc[4][2];
#pragma unroll
    for (int r = 0; r < 4; ++r) { acc[r][0] = 0.0f; acc[r][1] = 0.0f; }

#pragma unroll 2
    for (int m = 0; m < M_DIM; m += 4) {
      float wa[4], wb[4];
#pragma unroll
      for (int i = 0; i < 4; ++i) {
        wa[i] = w[(m + i) * M_DIM + j0];
        wb[i] = w[(m + i) * M_DIM + j0 + 256];
      }
#pragma unroll
      for (int r = 0; r < 4; ++r) {
        const float4 xv = *(const float4*)&xs[r0 + r][m];  // broadcast b128
        acc[r][0] += xv.x * wa[0] + xv.y * wa[1] + xv.z * wa[2] + xv.w * wa[3];
        acc[r][1] += xv.x * wb[0] + xv.y * wb[1] + xv.z * wb[2] + xv.w * wb[3];
      }
    }
#pragma unroll
    for (int r = 0; r < 4; ++r) {
      sm[r0 + r][j0]       = acc[r][0];
      sm[r0 + r][j0 + 256] = acc[r][1];
    }
  }
  __syncthreads();

  // ---- phase 3: softmax, one row per wave ----
  {
    const int r = t >> 6, ln = t & 63;
    float v[8];
    float mx = -INFINITY;
#pragma unroll
    for (int i = 0; i < 8; ++i) {
      v[i] = sm[r][ln + 64 * i];
      mx = fmaxf(mx, v[i]);
    }
#pragma unroll
    for (int s = 32; s > 0; s >>= 1) mx = fmaxf(mx, __shfl_xor(mx, s));
    float sum = 0.0f;
#pragma unroll
    for (int i = 0; i < 8; ++i) {
      v[i] = expf(v[i] - mx);
      sum += v[i];
    }
#pragma unroll
    for (int s = 32; s > 0; s >>= 1) sum += __shfl_xor(sum, s);
    const float inv = 1.0f / sum;
#pragma unroll
    for (int i = 0; i < 8; ++i) sm[r][ln + 64 * i] = v[i] * inv + EPSF;
  }
  __syncthreads();

  // ---- phase 4a: write scores_soft (plain b128 stores) ----
  {
    const f32x4* smv = (const f32x4*)&sm[0][0];
    f32x4* sg = (f32x4*)(soft + (size_t)k0 * M_DIM);
    sg[t]       = smv[t];
    sg[t + TPB] = smv[t + TPB];
  }

  // ---- phase 4b: combine, stream out/mw (2 MiB per block, plain stores) ----
  // global float4 index = k0*8192 + g, g = it*512 + t decomposes as
  // (r*512 + m)*16 + q -> perfectly coalesced stores.
  const f32x4* hard4 = (const f32x4*)hard;
  const size_t base = (size_t)k0 * (M_DIM * (N_DIM / 4));
#pragma unroll 4
  for (int it = 0; it < (ROWS * M_DIM * 16) / TPB; ++it) {
    const int g = it * TPB + t;
    const int q = g & 15;           // float4 index within n-row (fixed = t&15)
    const int pair = g >> 4;        // r*512 + m
    const int m = pair & (M_DIM - 1);
    const int r = pair >> 9;
    const float ss = sm[r][m];      // LDS broadcast (16 lanes/addr)
    const float xv = xs[r][m];
    const f32x4 sh = hard4[m * 16 + q];  // L2/L1-resident, 1 KiB/wave
    const f32x4 wgt = sh * ss;
    const f32x4 o = wgt * xv;
    out[base + g] = o;
    mw[base + g]  = wgt;
  }
}

// ---------------------------------------------------------------------------
extern "C" void kernel_launch(void* const* d_in, const int* in_sizes, int n_in,
                              void* d_out, int out_size, void* d_ws,
                              size_t ws_size, hipStream_t stream) {
  const float* x     = (const float*)d_in[0];
  const float* w_att = (const float*)d_in[1];
  const float* w_b   = (const float*)d_in[2];
  const int*   lptr  = (const int*)d_in[3];

  float* out_base = (float*)d_out;
  const size_t OUT_SZ = (size_t)K_DIM * M_DIM * N_DIM;  // 67,108,864
  float* out0 = out_base;                               // out [K,M,N]
  float* hard = out0 + OUT_SZ;                          // scores_hard [M,N]
  float* soft = hard + (size_t)M_DIM * N_DIM;           // scores_soft [K,M]
  float* mwp  = soft + (size_t)K_DIM * M_DIM;           // mask_weight [K,M,N]

  thr_hard_kernel<<<N_DIM, 256, 0, stream>>>(w_b, lptr, hard);
  fused_kernel<<<K_DIM / ROWS, TPB, 0, stream>>>(
      x, w_att, hard, soft, (f32x4*)out0, (f32x4*)mwp);
}